// Round 9
// baseline (156.943 us; speedup 1.0000x reference)
//
#include <hip/hip_runtime.h>
#include <hip/hip_fp16.h>

#define LOG2E 1.44269504088896340736f
#define DM 1536
#define LL  2048
#define NN  16
#define NCH 128    // chunks per row (2 waves x 64 lanes)
#define CL  16     // steps per chunk = LL / NCH

__device__ __forceinline__ float fexp2(float v){ return __builtin_amdgcn_exp2f(v); }
__device__ __forceinline__ float frcp(float v){ return __builtin_amdgcn_rcpf(v); }

// pack {d, x} as half2 in a float
__device__ __forceinline__ float packdx(float d, float x){
    return __builtin_bit_cast(float, __floats2half2_rn(d, x));
}
__device__ __forceinline__ void unpackdx(float f, float& d, float& x){
    const float2 p = __half22float2(__builtin_bit_cast(__half2, f));
    d = p.x; x = p.y;
}
// float4 = 8 packed halfs -> 8 floats
__device__ __forceinline__ void unpack8(const float4 f, float* o){
    float2 p;
    p = __half22float2(__builtin_bit_cast(__half2, f.x)); o[0]=p.x; o[1]=p.y;
    p = __half22float2(__builtin_bit_cast(__half2, f.y)); o[2]=p.x; o[3]=p.y;
    p = __half22float2(__builtin_bit_cast(__half2, f.z)); o[4]=p.x; o[5]=p.y;
    p = __half22float2(__builtin_bit_cast(__half2, f.w)); o[6]=p.x; o[7]=p.y;
}
// force a block-uniform float into an SGPR
__device__ __forceinline__ float to_sgpr(float v){
    return __builtin_bit_cast(float, __builtin_amdgcn_readfirstlane(__builtin_bit_cast(int, v)));
}

// B,C fp32 [b][n][t] -> fp16 records: record rec=(b*16+r)*128+c holds halfs
// [B n=0..15 | C n=0..15], t = c*16+r. Thread u = one 16B quarter-record:
// 8 stride-8KB dword gathers (L2-resident) + one coalesced dwordx4 store.
// (R8 evidence: transpose cost is small either way; wall gap ~89 us is fixed
// harness overhead, invariant across 9 configs. Kernel kept as R8.)
__global__ __launch_bounds__(256) void transpose_bc(
        const float* __restrict__ Bm, const float* __restrict__ Cm,
        __half* __restrict__ BC){
    const int u   = blockIdx.x*256 + threadIdx.x;  // 16384 quarter-records
    const int rec = u >> 2, q = u & 3;
    const int b   = rec >> 11;
    const int r   = (rec >> 7) & 15;
    const int c   = rec & 127;
    const int t   = c*16 + r;
    const float* src = (q & 2) ? Cm : Bm;          // q0,1 = B; q2,3 = C
    const int n0  = (q & 1) * 8;
    const long base = ((long)(b*NN + n0))*LL + t;
    __half h[8];
#pragma unroll
    for (int i=0;i<8;++i)
        h[i] = __float2half_rn(src[base + (long)i*LL]);
    ((float4*)BC)[u] = *(const float4*)h;
}

// Block = 2 waves = ONE row-pair (the R0 structural optimum; ledger R0-R8).
// R9 change (latency-only, zero numerics/traffic/structure delta vs R8):
//  - phases 1 & 3 use ROTATION prefetch: next BC record + next wd loaded into
//    registers at loop top, consumed next iteration (R6's pattern, which was
//    only ever tested confounded with the swizzle removal). Extends the
//    effective prefetch distance past the ~200-300cy L2 latency that the
//    in-loop unroll-2 loads only marginally covered at 3 waves/SIMD.
//  - phase 3's r=0 records (4 x float4) + wd are issued at the TOP of phase 2
//    so their L2 latency hides under the ~400cy KS shuffle scan, and the
//    barrier's vmcnt drain is free.
// Everything else identical to R8: XOR swizzle slot(r,c)=r*128+(c^r), raw
// {d,x} fp16 packing, A*LOG2E and D in SGPRs, unroll-2 loops, fp32 y stash,
// coalesced epilogue. LDS 16.5 KB; grid 1536 x 2 waves = 12 waves/CU resident.
__global__ __launch_bounds__(128, 3) void ssm_scan(
    const float* __restrict__ x, const float* __restrict__ delta,
    const float* __restrict__ A, const float* __restrict__ Dv,
    const float* __restrict__ z, const __half* __restrict__ BC,
    float* __restrict__ out)
{
    __shared__ float2 sdx[CL*NCH];     // 16 KB
    __shared__ float  wtot[2][2][NN];  // [P/G][row][n] from wave 0 lane 63

    const int lane = threadIdx.x & 63;
    const int w    = threadIdx.x >> 6;
    const int row0 = blockIdx.x*2;           // b*DM + d ; row1 = row0+1
    const int b    = (row0 >= DM) ? 1 : 0;
    const int d0   = row0 - b*DM;
    const int cmy  = w*64 + lane;            // my chunk (0..127)

    const long base0 = (long)row0*LL;
    const long base1 = base0 + LL;
    const float* gd0 = delta + base0; const float* gx0 = x + base0;
    const float* gd1 = delta + base1; const float* gx1 = x + base1;

    // ---- stage packed (d,x) for both rows; wave w covers t in [w*1024, +1024)
    for (int k=0;k<1024;k+=256){
        const int t0 = w*1024 + k + lane*4;
        const float4 dv0 = *(const float4*)(gd0 + t0);
        const float4 xv0 = *(const float4*)(gx0 + t0);
        const float4 dv1 = *(const float4*)(gd1 + t0);
        const float4 xv1 = *(const float4*)(gx1 + t0);
        const float dd0[4]={dv0.x,dv0.y,dv0.z,dv0.w}, xx0[4]={xv0.x,xv0.y,xv0.z,xv0.w};
        const float dd1[4]={dv1.x,dv1.y,dv1.z,dv1.w}, xx1[4]={xv1.x,xv1.y,xv1.z,xv1.w};
#pragma unroll
        for (int j=0;j<4;++j){
            const int t = t0 + j, r = t & 15, c = t >> 4;
            float2 wd; wd.x = packdx(dd0[j], xx0[j]); wd.y = packdx(dd1[j], xx1[j]);
            sdx[r*NCH + (c^r)] = wd;
        }
    }

    // record for (b, r, chunk cmy): BC + b*65536 + r*4096 + cmy*32 (halfs)
    const __half* bc = BC + (long)b*65536 + cmy*32;

    // A rows (x LOG2E) and D -> SGPRs (block-uniform)
    float A20[NN], A21[NN];
#pragma unroll
    for (int n=0;n<NN;++n){
        A20[n] = to_sgpr(A[d0*NN+n]     * LOG2E);
        A21[n] = to_sgpr(A[(d0+1)*NN+n] * LOG2E);
    }

    // ---- phase 1: local chunk scan h0=0 -> G (both rows); dsum -> P
    float G0[NN], G1[NN];
#pragma unroll
    for (int n=0;n<NN;++n){ G0[n]=0.f; G1[n]=0.f; }
    float ds0=0.f, ds1=0.f;
    {
        float4 rb0 = ((const float4*)bc)[0];
        float4 rb1 = ((const float4*)bc)[1];
        float2 wdc = sdx[cmy];                   // slot(0, cmy^0) = cmy
#pragma unroll 2
        for (int r=0;r<CL;++r){
            const int rn = (r<CL-1) ? r+1 : r;
            const float4* nrec = (const float4*)(bc + (long)rn*4096);
            const float4 nb0 = nrec[0], nb1 = nrec[1];
            const float2 nwd = sdx[rn*NCH + (cmy^rn)];

            float bb[16];
            unpack8(rb0, bb); unpack8(rb1, bb+8);
            float d_0,x_0,d_1,x_1;
            unpackdx(wdc.x, d_0, x_0); unpackdx(wdc.y, d_1, x_1);
            ds0 += d_0; ds1 += d_1;
            const float dx0 = d_0*x_0, dx1 = d_1*x_1;
#pragma unroll
            for (int n=0;n<NN;++n){
                const float e0 = fexp2(d_0*A20[n]);
                G0[n] = __builtin_fmaf(e0, G0[n], bb[n]*dx0);
                const float e1 = fexp2(d_1*A21[n]);
                G1[n] = __builtin_fmaf(e1, G1[n], bb[n]*dx1);
            }
            rb0 = nb0; rb1 = nb1; wdc = nwd;
        }
    }

    // ---- phase 2: two-level scan
    float h0[NN], h1[NN];
    float4 rb0p, rb1p, rc0p, rc1p; float2 wd0p;
    {
        // pre-issue phase-3's r=0 loads: L2 latency hides under the KS scan,
        // and the barrier's vmcnt drain is then free.
        rb0p = ((const float4*)bc)[0];
        rb1p = ((const float4*)bc)[1];
        rc0p = ((const float4*)bc)[2];
        rc1p = ((const float4*)bc)[3];
        wd0p = sdx[cmy];

        float P0[NN], P1[NN];
#pragma unroll
        for (int n=0;n<NN;++n){ P0[n]=fexp2(ds0*A20[n]); P1[n]=fexp2(ds1*A21[n]); }
        // inclusive Kogge-Stone within wave
#pragma unroll
        for (int s=1;s<64;s<<=1){
#pragma unroll
            for (int n=0;n<NN;++n){
                const float pl0=__shfl_up(P0[n],s), gl0=__shfl_up(G0[n],s);
                const float pl1=__shfl_up(P1[n],s), gl1=__shfl_up(G1[n],s);
                if (lane >= s){
                    G0[n]=__builtin_fmaf(P0[n],gl0,G0[n]); P0[n]*=pl0;
                    G1[n]=__builtin_fmaf(P1[n],gl1,G1[n]); P1[n]*=pl1;
                }
            }
        }
        // wave-0 totals -> LDS
        if (w==0 && lane==63){
#pragma unroll
            for (int n=0;n<NN;++n){
                wtot[0][0][n]=P0[n]; wtot[1][0][n]=G0[n];
                wtot[0][1][n]=P1[n]; wtot[1][1][n]=G1[n];
            }
        }
        __syncthreads();
        // exclusive within wave, then compose with wave-0 total (wave 1 only)
#pragma unroll
        for (int n=0;n<NN;++n){
            const float pe0=__shfl_up(P0[n],1), ge0=__shfl_up(G0[n],1);
            const float pe1=__shfl_up(P1[n],1), ge1=__shfl_up(G1[n],1);
            const float Px0 = (lane==0)?1.f:pe0, Gx0 = (lane==0)?0.f:ge0;
            const float Px1 = (lane==0)?1.f:pe1, Gx1 = (lane==0)?0.f:ge1;
            const float Gt0 = (w==0)?0.f:wtot[1][0][n];
            const float Gt1 = (w==0)?0.f:wtot[1][1][n];
            h0[n] = __builtin_fmaf(Px0, Gt0, Gx0);
            h1[n] = __builtin_fmaf(Px1, Gt1, Gx1);
        }
    }

    // ---- phase 3: re-scan with true h_start; stash fp32 {y0+x0*D0, y1+x1*D1}
    const float Dd0 = to_sgpr(Dv[d0]), Dd1 = to_sgpr(Dv[d0+1]);
    {
        float4 rb0 = rb0p, rb1 = rb1p, rc0 = rc0p, rc1 = rc1p;
        float2 wdc = wd0p;
#pragma unroll 2
        for (int r=0;r<CL;++r){
            const int rn = (r<CL-1) ? r+1 : r;
            const float4* nrec = (const float4*)(bc + (long)rn*4096);
            const float4 nb0 = nrec[0], nb1 = nrec[1];
            const float4 nc0 = nrec[2], nc1 = nrec[3];
            const float2 nwd = sdx[rn*NCH + (cmy^rn)]; // row rn written at iter rn (later): safe

            float bb[16], cc[16];
            unpack8(rb0, bb); unpack8(rb1, bb+8);
            unpack8(rc0, cc); unpack8(rc1, cc+8);
            float d_0,x_0,d_1,x_1;
            unpackdx(wdc.x, d_0, x_0); unpackdx(wdc.y, d_1, x_1);
            const float dx0 = d_0*x_0, dx1 = d_1*x_1;
            float ya0=0.f, yb0=0.f, ya1=0.f, yb1=0.f;
#pragma unroll
            for (int n=0;n<NN;n+=2){
                const float e0a = fexp2(d_0*A20[n]);
                h0[n]  =__builtin_fmaf(e0a,h0[n],  bb[n]*dx0);   ya0=__builtin_fmaf(h0[n],  cc[n],  ya0);
                const float e0b = fexp2(d_0*A20[n+1]);
                h0[n+1]=__builtin_fmaf(e0b,h0[n+1],bb[n+1]*dx0); yb0=__builtin_fmaf(h0[n+1],cc[n+1],yb0);
                const float e1a = fexp2(d_1*A21[n]);
                h1[n]  =__builtin_fmaf(e1a,h1[n],  bb[n]*dx1);   ya1=__builtin_fmaf(h1[n],  cc[n],  ya1);
                const float e1b = fexp2(d_1*A21[n+1]);
                h1[n+1]=__builtin_fmaf(e1b,h1[n+1],bb[n+1]*dx1); yb1=__builtin_fmaf(h1[n+1],cc[n+1],yb1);
            }
            float2 yo;
            yo.x = __builtin_fmaf(x_0, Dd0, ya0+yb0);
            yo.y = __builtin_fmaf(x_1, Dd1, ya1+yb1);
            sdx[r*NCH + (cmy^r)] = yo;          // same-wave slot, no barrier
            rb0=nb0; rb1=nb1; rc0=nc0; rc1=nc1; wdc=nwd;
        }
    }

    // ---- epilogue: stream z once per row, coalesced float4 in/out
    const float* gz0 = z + base0; const float* gz1 = z + base1;
    float* go0 = out + base0;     float* go1 = out + base1;
    for (int k=0;k<1024;k+=256){
        const int t0 = w*1024 + k + lane*4;
        const float4 zv0 = *(const float4*)(gz0 + t0);
        const float4 zv1 = *(const float4*)(gz1 + t0);
        const float zz0[4]={zv0.x,zv0.y,zv0.z,zv0.w}, zz1[4]={zv1.x,zv1.y,zv1.z,zv1.w};
        float o0[4], o1[4];
#pragma unroll
        for (int j=0;j<4;++j){
            const int t = t0 + j, r = t & 15, c = t >> 4;
            const float2 wd = sdx[r*NCH + (c^r)];
            const float s0 = frcp(1.f + fexp2(-zz0[j]*LOG2E));
            const float s1 = frcp(1.f + fexp2(-zz1[j]*LOG2E));
            o0[j] = wd.x * (zz0[j]*s0);
            o1[j] = wd.y * (zz1[j]*s1);
        }
        float4 a  = {o0[0],o0[1],o0[2],o0[3]};
        float4 bq = {o1[0],o1[1],o1[2],o1[3]};
        *(float4*)(go0 + t0) = a;
        *(float4*)(go1 + t0) = bq;
    }
}

extern "C" void kernel_launch(void* const* d_in, const int* in_sizes, int n_in,
                              void* d_out, int out_size, void* d_ws, size_t ws_size,
                              hipStream_t stream) {
    const float* x     = (const float*)d_in[0];
    const float* delta = (const float*)d_in[1];
    const float* A     = (const float*)d_in[2];
    const float* B     = (const float*)d_in[3];
    const float* C     = (const float*)d_in[4];
    const float* Dv    = (const float*)d_in[5];
    const float* z     = (const float*)d_in[6];
    float* out = (float*)d_out;

    __half* BC = (__half*)d_ws;               // 131072 halfs = 256 KB

    transpose_bc<<<dim3(64), dim3(256), 0, stream>>>(B, C, BC);
    ssm_scan<<<dim3(DM), dim3(128), 0, stream>>>(x, delta, A, Dv, z, BC, out);
}